// Round 1
// 191.319 us; speedup vs baseline: 1.0881x; 1.0881x over previous
//
#include <hip/hip_runtime.h>
#include <hip/hip_bf16.h>
#include <stdint.h>

// Problem constants (fixed by reference setup_inputs)
constexpr int E_NUM  = 8;
constexpr int I_DIM  = 1024;
constexpr int O_DIM  = 1024;
constexpr int B_SEG  = 16;
constexpr int N_ROWS = 16384;

// GEMM tiling: 256x256 tile, BK=64, 512 threads = 8 waves (2 M x 4 N)
constexpr int BM = 256, BN = 256, BK = 64;
constexpr int NT = I_DIM / BK;          // 16 K-tiles

typedef __bf16 bf16x8 __attribute__((ext_vector_type(8)));
typedef float  f32x4  __attribute__((ext_vector_type(4)));
typedef unsigned short ushortx8 __attribute__((ext_vector_type(8)));

__device__ __forceinline__ unsigned short f2bf(float f) {
    unsigned int u = __float_as_uint(f);
    u += 0x7fffu + ((u >> 16) & 1u);
    return (unsigned short)(u >> 16);
}

// ---------------------------------------------------------------------------
// Kernel 1: x fp32 -> bf16. 64B in / 32B out per thread.
// ---------------------------------------------------------------------------
__global__ __launch_bounds__(256) void cvt_x(const float* __restrict__ x,
                                             unsigned short* __restrict__ xb) {
    size_t idx = ((size_t)blockIdx.x * 256 + threadIdx.x) * 16;
    const float4* p = (const float4*)(x + idx);
    float4 v0 = p[0], v1 = p[1], v2 = p[2], v3 = p[3];
    ushortx8 o0, o1;
    o0[0] = f2bf(v0.x); o0[1] = f2bf(v0.y); o0[2] = f2bf(v0.z); o0[3] = f2bf(v0.w);
    o0[4] = f2bf(v1.x); o0[5] = f2bf(v1.y); o0[6] = f2bf(v1.z); o0[7] = f2bf(v1.w);
    o1[0] = f2bf(v2.x); o1[1] = f2bf(v2.y); o1[2] = f2bf(v2.z); o1[3] = f2bf(v2.w);
    o1[4] = f2bf(v3.x); o1[5] = f2bf(v3.y); o1[6] = f2bf(v3.z); o1[7] = f2bf(v3.w);
    *(ushortx8*)(xb + idx)     = o0;
    *(ushortx8*)(xb + idx + 8) = o1;
}

// ---------------------------------------------------------------------------
// Kernel 2: W_b[o,i] = sum_e coeff[b,e] * weights[e,o,i], bf16 out.
// ---------------------------------------------------------------------------
__global__ __launch_bounds__(256) void synth_w(const float* __restrict__ w,
                                               const float* __restrict__ coeff,
                                               unsigned short* __restrict__ wb) {
    __shared__ float sc[B_SEG * E_NUM];
    int tid = threadIdx.x;
    if (tid < B_SEG * E_NUM) sc[tid] = coeff[tid];
    __syncthreads();

    size_t idx = ((size_t)blockIdx.x * 256 + tid) * 8;   // into [O*I)
    float4 wv0[E_NUM], wv1[E_NUM];
#pragma unroll
    for (int e = 0; e < E_NUM; e++) {
        const float4* p = (const float4*)(w + (size_t)e * O_DIM * I_DIM + idx);
        wv0[e] = p[0];
        wv1[e] = p[1];
    }

#pragma unroll
    for (int b = 0; b < B_SEG; b++) {
        float a[8] = {0,0,0,0,0,0,0,0};
#pragma unroll
        for (int e = 0; e < E_NUM; e++) {
            float c = sc[b * E_NUM + e];
            a[0] += c * wv0[e].x; a[1] += c * wv0[e].y;
            a[2] += c * wv0[e].z; a[3] += c * wv0[e].w;
            a[4] += c * wv1[e].x; a[5] += c * wv1[e].y;
            a[6] += c * wv1[e].z; a[7] += c * wv1[e].w;
        }
        ushortx8 o;
#pragma unroll
        for (int j = 0; j < 8; j++) o[j] = f2bf(a[j]);
        *(ushortx8*)(wb + (size_t)b * O_DIM * I_DIM + idx) = o;
    }
}

// ---------------------------------------------------------------------------
// opaque LDS read: compiler must not see this as aliasing global_load_lds
// writes (would insert vmcnt(0)); manual lgkmcnt + sched_barrier per rule 18.
// ---------------------------------------------------------------------------
__device__ __forceinline__ bf16x8 lds_read_b128(unsigned addr) {
    bf16x8 r;
    asm volatile("ds_read_b128 %0, %1" : "=v"(r) : "v"(addr));
    return r;
}

// ---------------------------------------------------------------------------
// Kernel 3: per-segment GEMM, C = X * W_seg^T + bias.
// 256x256 tile, BK=64, 8 waves (2x4), each wave owns a 128x64 sub-tile.
// LDS double-buffer (2 x 64 KB); counted vmcnt keeps the next tile's 8
// global_load_lds in flight across raw s_barriers (T3+T4); K-chunk XOR
// swizzle on the staged GLOBAL source + same involution on ds_read (T2);
// setprio(1) around each 32-MFMA cluster (T5).
// ---------------------------------------------------------------------------
__global__ __launch_bounds__(512, 2) void gemm_moe(
    const unsigned short* __restrict__ xb,   // [N][I] bf16 bits
    const unsigned short* __restrict__ wb,   // [B][O][I] bf16 bits
    const float* __restrict__ bias,          // [O]
    const int* __restrict__ msz,             // [B]
    float* __restrict__ out)                 // [N][O] fp32
{
    __shared__ __align__(16) unsigned short sA[2][BM * BK];   // 2 x 32 KB
    __shared__ __align__(16) unsigned short sB[2][BN * BK];   // 2 x 32 KB

    // ---- XCD-aware mapping: 256 blocks, lid%8 = XCD, 2 segments per XCD,
    // 4x4 tiles of 256^2 per segment.
    const int lid  = blockIdx.x;            // 0..255
    const int xcd  = lid & 7;
    const int idx  = lid >> 3;              // 0..31
    const int seg  = (xcd << 1) | (idx >> 4);
    const int t    = idx & 15;
    const int mblk = t >> 2;
    const int nblk = t & 3;

    int off = 0;
    for (int b = 0; b < seg; b++) off += msz[b];
    const int row0 = off + mblk * BM;
    const int col0 = nblk * BN;
    const unsigned short* wseg = wb + (size_t)seg * O_DIM * I_DIM;

    const int tid  = threadIdx.x;
    const int wave = tid >> 6;              // 0..7
    const int lane = tid & 63;
    const int wr = wave >> 2, wc = wave & 3;
    const int quad = lane >> 4, l16 = lane & 15;

    // ---- staging: per wave, rows [wave*32, wave*32+32) of both tiles,
    // 4 global_load_lds each for A and B per K-tile (8 rows per instr).
    // LDS dest is linear; the XOR swizzle (chunk ^= row&7 within the
    // 8-chunk row) is applied to the per-lane GLOBAL source address.
    const int srow   = lane >> 3;                    // 0..7
    const int schunk = (lane & 7) ^ srow;            // swizzled K-chunk
    const unsigned short* gA = xb   + (size_t)(row0 + wave * 32 + srow) * I_DIM + schunk * 8;
    const unsigned short* gB = wseg + (size_t)(col0 + wave * 32 + srow) * I_DIM + schunk * 8;

    // ---- LDS read addresses (bytes). Row stride = 128 B; chunk position
    // for K-chunk q of row r is q ^ (r&7); r&7 == l16&7 for all fragments.
    const unsigned ldsA0 = (unsigned)(size_t)((__attribute__((address_space(3))) unsigned short*)&sA[0][0]);
    const unsigned ldsB0 = (unsigned)(size_t)((__attribute__((address_space(3))) unsigned short*)&sB[0][0]);
    constexpr unsigned BUFB = (unsigned)(BM * BK * 2);        // 32768 B / buffer
    const unsigned rp0 = (unsigned)(((quad    ) ^ (l16 & 7)) * 16);  // kk=0
    const unsigned rp1 = (unsigned)(((quad + 4) ^ (l16 & 7)) * 16);  // kk=1
    const unsigned rowA = (unsigned)((wr * 128 + l16) * 128);
    const unsigned rowB = (unsigned)((wc * 64  + l16) * 128);
    const unsigned rdA0 = ldsA0 + rowA + rp0, rdA1 = ldsA0 + rowA + rp1;
    const unsigned rdB0 = ldsB0 + rowB + rp0, rdB1 = ldsB0 + rowB + rp1;

#define STAGE_TILE(CUR, K0)                                                            \
    do {                                                                               \
        _Pragma("unroll")                                                              \
        for (int j_ = 0; j_ < 4; ++j_) {                                               \
            __builtin_amdgcn_global_load_lds(                                          \
                (const __attribute__((address_space(1))) void*)(gA + (K0) + j_ * 8 * I_DIM), \
                (__attribute__((address_space(3))) void*)(&sA[(CUR)][(wave * 32 + j_ * 8) * BK]), \
                16, 0, 0);                                                             \
            __builtin_amdgcn_global_load_lds(                                          \
                (const __attribute__((address_space(1))) void*)(gB + (K0) + j_ * 8 * I_DIM), \
                (__attribute__((address_space(3))) void*)(&sB[(CUR)][(wave * 32 + j_ * 8) * BK]), \
                16, 0, 0);                                                             \
        }                                                                              \
    } while (0)

    f32x4 acc[8][4];
#pragma unroll
    for (int m = 0; m < 8; ++m)
#pragma unroll
        for (int n = 0; n < 4; ++n)
            acc[m][n] = (f32x4){0.f, 0.f, 0.f, 0.f};

    // ---- prologue: tiles 0 and 1 in flight; wait only for tile 0 (8 newest
    // loads stay outstanding across the barrier).
    STAGE_TILE(0, 0);
    STAGE_TILE(1, BK);
    asm volatile("s_waitcnt vmcnt(8)");
    __builtin_amdgcn_sched_barrier(0);
    __builtin_amdgcn_s_barrier();

#pragma unroll 2
    for (int kt = 0; kt < NT; ++kt) {
        const int cur = kt & 1;
        const unsigned bo = (unsigned)cur * BUFB;

        bf16x8 af[8], bfr[4];

        // ---- phase kk = 0 ----
#pragma unroll
        for (int m = 0; m < 8; ++m) af[m] = lds_read_b128(rdA0 + bo + m * 2048);
#pragma unroll
        for (int n = 0; n < 4; ++n) bfr[n] = lds_read_b128(rdB0 + bo + n * 2048);
        asm volatile("s_waitcnt lgkmcnt(0)");
        __builtin_amdgcn_sched_barrier(0);
        __builtin_amdgcn_s_setprio(1);
#pragma unroll
        for (int m = 0; m < 8; ++m)
#pragma unroll
            for (int n = 0; n < 4; ++n)
                acc[m][n] = __builtin_amdgcn_mfma_f32_16x16x32_bf16(
                    af[m], bfr[n], acc[m][n], 0, 0, 0);
        __builtin_amdgcn_s_setprio(0);
        __builtin_amdgcn_sched_barrier(0);

        // ---- phase kk = 1 ----
#pragma unroll
        for (int m = 0; m < 8; ++m) af[m] = lds_read_b128(rdA1 + bo + m * 2048);
#pragma unroll
        for (int n = 0; n < 4; ++n) bfr[n] = lds_read_b128(rdB1 + bo + n * 2048);
        asm volatile("s_waitcnt lgkmcnt(0)");
        __builtin_amdgcn_sched_barrier(0);
        __builtin_amdgcn_s_setprio(1);
#pragma unroll
        for (int m = 0; m < 8; ++m)
#pragma unroll
            for (int n = 0; n < 4; ++n)
                acc[m][n] = __builtin_amdgcn_mfma_f32_16x16x32_bf16(
                    af[m], bfr[n], acc[m][n], 0, 0, 0);
        __builtin_amdgcn_s_setprio(0);
        __builtin_amdgcn_sched_barrier(0);

        // ---- advance: free buf[cur], stage tile kt+2 into it, then wait
        // (counted) for tile kt+1 — its 8 loads are the oldest outstanding.
        if (kt < NT - 1) {
            __builtin_amdgcn_s_barrier();          // all waves done reading buf[cur]
            if (kt < NT - 2) {
                STAGE_TILE(cur, (kt + 2) * BK);
                asm volatile("s_waitcnt vmcnt(8)");  // tile kt+1 landed; kt+2 in flight
            } else {
                asm volatile("s_waitcnt vmcnt(0)");  // tail: drain last tile
            }
            __builtin_amdgcn_sched_barrier(0);
            __builtin_amdgcn_s_barrier();          // buf[cur^1] ready for everyone
        }
    }
#undef STAGE_TILE

    // ---- epilogue: C/D layout col=lane&15, row=quad*4+reg ----
    float bv[4];
#pragma unroll
    for (int n = 0; n < 4; ++n)
        bv[n] = bias[col0 + wc * 64 + n * 16 + l16];

#pragma unroll
    for (int m = 0; m < 8; ++m) {
#pragma unroll
        for (int r = 0; r < 4; ++r) {
            int row = row0 + wr * 128 + m * 16 + quad * 4 + r;
            float* po = out + (size_t)row * O_DIM + col0 + wc * 64 + l16;
#pragma unroll
            for (int n = 0; n < 4; ++n)
                po[n * 16] = acc[m][n][r] + bv[n];
        }
    }
}

// ---------------------------------------------------------------------------
extern "C" void kernel_launch(void* const* d_in, const int* in_sizes, int n_in,
                              void* d_out, int out_size, void* d_ws, size_t ws_size,
                              hipStream_t stream) {
    const float* x     = (const float*)d_in[0];
    const float* w     = (const float*)d_in[1];
    const float* bias  = (const float*)d_in[2];
    const float* coeff = (const float*)d_in[3];
    const int*   msz   = (const int*)d_in[4];
    float* out = (float*)d_out;

    unsigned short* xb = (unsigned short*)d_ws;                    // 32 MB
    unsigned short* wb = xb + (size_t)N_ROWS * I_DIM;              // 32 MB

    int cvt_blocks   = (int)(((size_t)N_ROWS * I_DIM) / (256 * 16));  // 4096
    int synth_blocks = (int)(((size_t)O_DIM * I_DIM) / (256 * 8));    // 512

    cvt_x<<<cvt_blocks, 256, 0, stream>>>(x, xb);
    synth_w<<<synth_blocks, 256, 0, stream>>>(w, coeff, wb);

    gemm_moe<<<B_SEG * (1024 / BM) * (1024 / BN), 512, 0, stream>>>(xb, wb, bias, msz, out);
}